// Round 14
// baseline (1495.186 us; speedup 1.0000x reference)
//
#include <hip/hip_runtime.h>
#include <math.h>

#define Bq 32
#define Sq 512
#define Tq 32
#define EMBq 256
#define HIDq 512
#define VOCABq 50000
#define OOVq 100
#define VEXTq (VOCABq + OOVq)

typedef unsigned short u16;
typedef unsigned long long u64;
typedef __attribute__((ext_vector_type(8))) short bf16x8;
typedef __attribute__((ext_vector_type(4))) float f32x4;

__device__ __forceinline__ float sigmoidf_(float x){ return 1.0f/(1.0f+__expf(-x)); }
__device__ __forceinline__ float tanhf_(float x){ return 1.0f - 2.0f/(__expf(2.0f*x)+1.0f); }

__device__ __forceinline__ u16 f2bf(float x){
  union{float f; unsigned u;} v; v.f=x;
  unsigned r = v.u + 0x7FFFu + ((v.u>>16)&1u);
  return (u16)(r>>16);
}
__device__ __forceinline__ float bf2f(u16 h){
  union{unsigned u; float f;} v; v.u = ((unsigned)h)<<16; return v.f;
}

// ---- agent-scope (L2-bypass, device-coherent) accessors ----
__device__ __forceinline__ float ld1(const float* p){
  return __hip_atomic_load((float*)p, __ATOMIC_RELAXED, __HIP_MEMORY_SCOPE_AGENT);
}
__device__ __forceinline__ void st1(float* p, float v){
  __hip_atomic_store(p, v, __ATOMIC_RELAXED, __HIP_MEMORY_SCOPE_AGENT);
}
__device__ __forceinline__ float2 ld2(const float* p){
  u64 v = __hip_atomic_load((u64*)p, __ATOMIC_RELAXED, __HIP_MEMORY_SCOPE_AGENT);
  union{u64 u; float2 f;} c; c.u=v; return c.f;
}
__device__ __forceinline__ void atadd(float* p, float v){
  __hip_atomic_fetch_add(p, v, __ATOMIC_RELAXED, __HIP_MEMORY_SCOPE_AGENT);
}

// ---- group-local barrier: 8 blocks, distributed slots ----
__device__ __forceinline__ void mbar(unsigned* gs, int sc, unsigned tag){
  asm volatile("s_waitcnt vmcnt(0)" ::: "memory");
  __syncthreads();
  if (threadIdx.x==0)
    __hip_atomic_store(gs+sc, tag, __ATOMIC_RELAXED, __HIP_MEMORY_SCOPE_AGENT);
  if (threadIdx.x<64){
    for(;;){
      unsigned v = (threadIdx.x<8)
        ? __hip_atomic_load(gs+threadIdx.x, __ATOMIC_RELAXED, __HIP_MEMORY_SCOPE_AGENT)
        : tag;
      if (__all(v>=tag)) break;
      __builtin_amdgcn_s_sleep(1);
    }
  }
  __syncthreads();
}

__device__ __forceinline__ float blockSum512(float v, float* red){
  #pragma unroll
  for (int off=32; off>0; off>>=1) v += __shfl_down(v, off);
  int lane = threadIdx.x & 63, wid = threadIdx.x >> 6;
  __syncthreads();
  if (lane==0) red[wid]=v;
  __syncthreads();
  float t=0.f;
  #pragma unroll
  for (int w=0;w<8;++w) t+=red[w];
  return t;
}

// ---- merged prep: WET/WkT/WoT transposes + WAbf convert ----
__global__ __launch_bounds__(256) void k_prep(
    const float* __restrict__ W_enc, u16* __restrict__ WET,
    const float* __restrict__ Wk,    u16* __restrict__ WkT,
    const float* __restrict__ W_out, u16* __restrict__ WoT,
    const float* __restrict__ W_attn,u16* __restrict__ WAbf){
  __shared__ float T[32][33];
  const int bid = blockIdx.x, tid = threadIdx.x;
  if (bid < 1792){
    const float* in; u16* out; int ldin, ldout, n0, k0;
    if (bid < 256){ in=W_enc; out=WET; ldin=512; ldout=512;
      n0=(bid&15)*32; k0=(bid>>4)*32; }
    else if (bid < 1280){ int b=bid-256; in=Wk; out=WkT; ldin=2048; ldout=512;
      n0=(b&63)*32; k0=(b>>6)*32; }
    else { int b=bid-1280; in=W_out; out=WoT; ldin=512; ldout=1024;
      n0=(b&15)*32; k0=(b>>4)*32; }
    #pragma unroll
    for (int it=0; it<4; ++it){
      int id=tid+it*256; int kk=id>>5, nn=id&31;
      T[kk][nn] = in[(size_t)(k0+kk)*ldin + n0+nn];
    }
    __syncthreads();
    #pragma unroll
    for (int it=0; it<4; ++it){
      int id=tid+it*256; int nn=id>>5, kk=id&31;
      out[(size_t)(n0+nn)*ldout + k0+kk] = f2bf(T[kk][nn]);
    }
  } else {
    int i = (bid-1792)*256 + tid;
    WAbf[i] = f2bf(W_attn[i]);
  }
}

// ---- Xb[j][i] = bf16(W_x[256+j][i]); Wxp[j] = sum_i W_x[256+j][i]*Wpgen[1536+i] ----
__global__ __launch_bounds__(512) void k_wx2c(const float* __restrict__ W_x,
    const float* __restrict__ Wpgen, u16* __restrict__ Xb, float* __restrict__ Wxp){
  __shared__ float red[8];
  const int j = blockIdx.x, i = threadIdx.x;
  float v = W_x[(size_t)(256+j)*512 + i];
  Xb[(size_t)j*512 + i] = f2bf(v);
  float s = blockSum512(v*Wpgen[1536+i], red);
  if (i==0) Wxp[j] = s;
}

// ---- generic MFMA GEMM (K=512): out f32 [M][ncols] = A@B^T (+bias) ----
__global__ __launch_bounds__(256) void k_gemm512(const u16* __restrict__ A,
    const u16* __restrict__ B, const float* __restrict__ bias,
    float* __restrict__ out, int ncols, int use_bias){
  __shared__ u16 As[128*40];
  __shared__ u16 Bs[128*40];
  const int tid = threadIdx.x;
  const int m0 = blockIdx.x * 128;
  const int n0 = blockIdx.y * 128;
  const int wid = tid>>6, lane = tid&63;
  const int wm = (wid>>1)*64, wn = (wid&1)*64;
  const int l15 = lane&15, l4 = lane>>4;
  f32x4 acc[4][4];
  #pragma unroll
  for (int mi=0;mi<4;++mi)
    #pragma unroll
    for (int ni=0;ni<4;++ni) acc[mi][ni] = (f32x4){0.f,0.f,0.f,0.f};
  for (int kt=0; kt<16; ++kt){
    const int k0 = kt*32;
    __syncthreads();
    #pragma unroll
    for (int it=0; it<2; ++it){
      int id = tid + it*256;
      int row = id>>2, c4 = id&3;
      uint4 va = *(const uint4*)(A + (size_t)(m0+row)*512 + k0 + c4*8);
      *(uint4*)(&As[row*40 + c4*8]) = va;
      uint4 vb = *(const uint4*)(B + (size_t)(n0+row)*512 + k0 + c4*8);
      *(uint4*)(&Bs[row*40 + c4*8]) = vb;
    }
    __syncthreads();
    bf16x8 a[4], b[4];
    #pragma unroll
    for (int mi=0;mi<4;++mi) a[mi] = *(const bf16x8*)(&As[(wm+mi*16+l15)*40 + l4*8]);
    #pragma unroll
    for (int ni=0;ni<4;++ni) b[ni] = *(const bf16x8*)(&Bs[(wn+ni*16+l15)*40 + l4*8]);
    #pragma unroll
    for (int mi=0;mi<4;++mi)
      #pragma unroll
      for (int ni=0;ni<4;++ni)
        acc[mi][ni] = __builtin_amdgcn_mfma_f32_16x16x32_bf16(a[mi], b[ni], acc[mi][ni], 0,0,0);
  }
  #pragma unroll
  for (int ni=0;ni<4;++ni){
    const int col = n0 + wn + ni*16 + l15;
    const float bp = use_bias ? bias[col] : 0.f;
    #pragma unroll
    for (int mi=0;mi<4;++mi){
      const int rbase = m0 + wm + mi*16 + l4*4;
      #pragma unroll
      for (int r=0;r<4;++r)
        out[(size_t)(rbase+r)*ncols + col] = acc[mi][ni][r] + bp;
    }
  }
}

// ---- generic-K MFMA GEMM, bf16 out ----
__global__ __launch_bounds__(256) void k_gemmb(const u16* __restrict__ A,
    const u16* __restrict__ B, u16* __restrict__ out, int K, int N){
  __shared__ u16 As[128*40];
  __shared__ u16 Bs[128*40];
  const int tid = threadIdx.x;
  const int m0 = blockIdx.x * 128;
  const int n0 = blockIdx.y * 128;
  const int wid = tid>>6, lane = tid&63;
  const int wm = (wid>>1)*64, wn = (wid&1)*64;
  const int l15 = lane&15, l4 = lane>>4;
  f32x4 acc[4][4];
  #pragma unroll
  for (int mi=0;mi<4;++mi)
    #pragma unroll
    for (int ni=0;ni<4;++ni) acc[mi][ni] = (f32x4){0.f,0.f,0.f,0.f};
  const int kts = K>>5;
  for (int kt=0; kt<kts; ++kt){
    const int k0 = kt*32;
    __syncthreads();
    #pragma unroll
    for (int it=0; it<2; ++it){
      int id = tid + it*256;
      int row = id>>2, c4 = id&3;
      uint4 va = *(const uint4*)(A + (size_t)(m0+row)*K + k0 + c4*8);
      *(uint4*)(&As[row*40 + c4*8]) = va;
      uint4 vb = *(const uint4*)(B + (size_t)(n0+row)*K + k0 + c4*8);
      *(uint4*)(&Bs[row*40 + c4*8]) = vb;
    }
    __syncthreads();
    bf16x8 a[4], b[4];
    #pragma unroll
    for (int mi=0;mi<4;++mi) a[mi] = *(const bf16x8*)(&As[(wm+mi*16+l15)*40 + l4*8]);
    #pragma unroll
    for (int ni=0;ni<4;++ni) b[ni] = *(const bf16x8*)(&Bs[(wn+ni*16+l15)*40 + l4*8]);
    #pragma unroll
    for (int mi=0;mi<4;++mi)
      #pragma unroll
      for (int ni=0;ni<4;++ni)
        acc[mi][ni] = __builtin_amdgcn_mfma_f32_16x16x32_bf16(a[mi], b[ni], acc[mi][ni], 0,0,0);
  }
  #pragma unroll
  for (int ni=0;ni<4;++ni){
    const int col = n0 + wn + ni*16 + l15;
    #pragma unroll
    for (int mi=0;mi<4;++mi){
      const int rbase = m0 + wm + mi*16 + l4*4;
      #pragma unroll
      for (int r=0;r<4;++r)
        out[(size_t)(rbase+r)*N + col] = f2bf(acc[mi][ni][r]);
    }
  }
}

// ---- EFbf = bf16( es @ W_enc + b_enc ), MFMA ----
__global__ __launch_bounds__(256) void k_encm(const float* __restrict__ es,
    const u16* __restrict__ WET, const float* __restrict__ b_enc,
    u16* __restrict__ EFbf){
  __shared__ u16 As[128*40];
  __shared__ u16 Bs[128*40];
  const int tid=threadIdx.x;
  const int m0 = blockIdx.x*128, n0 = blockIdx.y*128;
  const int wid=tid>>6, lane=tid&63;
  const int wm=(wid>>1)*64, wn=(wid&1)*64;
  const int l15=lane&15, l4=lane>>4;
  f32x4 acc[4][4];
  #pragma unroll
  for (int mi=0;mi<4;++mi)
    #pragma unroll
    for (int ni=0;ni<4;++ni) acc[mi][ni] = (f32x4){0.f,0.f,0.f,0.f};
  for (int kt=0; kt<16; ++kt){
    const int k0=kt*32;
    __syncthreads();
    #pragma unroll
    for (int it=0; it<4; ++it){
      int id=tid+it*256; int row=id>>3, q=id&7;
      float4 v = *(const float4*)(es + (size_t)(m0+row)*512 + k0 + q*4);
      u64 pk = (u64)f2bf(v.x) | ((u64)f2bf(v.y)<<16) | ((u64)f2bf(v.z)<<32) | ((u64)f2bf(v.w)<<48);
      *(u64*)&As[row*40 + q*4] = pk;
    }
    #pragma unroll
    for (int it=0; it<2; ++it){
      int id=tid+it*256; int row=id>>2, c4=id&3;
      uint4 v = *(const uint4*)(WET + (size_t)(n0+row)*512 + k0 + c4*8);
      *(uint4*)&Bs[row*40 + c4*8] = v;
    }
    __syncthreads();
    bf16x8 a[4], b[4];
    #pragma unroll
    for (int mi=0;mi<4;++mi) a[mi] = *(const bf16x8*)(&As[(wm+mi*16+l15)*40 + l4*8]);
    #pragma unroll
    for (int ni=0;ni<4;++ni) b[ni] = *(const bf16x8*)(&Bs[(wn+ni*16+l15)*40 + l4*8]);
    #pragma unroll
    for (int mi=0;mi<4;++mi)
      #pragma unroll
      for (int ni=0;ni<4;++ni)
        acc[mi][ni] = __builtin_amdgcn_mfma_f32_16x16x32_bf16(a[mi], b[ni], acc[mi][ni], 0,0,0);
  }
  #pragma unroll
  for (int ni=0;ni<4;++ni){
    const int col = n0+wn+ni*16+l15;
    const float bp = b_enc[col];
    #pragma unroll
    for (int mi=0;mi<4;++mi){
      const int rb = m0+wm+mi*16+l4*4;
      #pragma unroll
      for (int r=0;r<4;++r)
        EFbf[(size_t)(rb+r)*512 + col] = f2bf(acc[mi][ni][r]+bp);
    }
  }
}

// ---- embx_bf (bf16) + embxp ----
__global__ __launch_bounds__(512) void k_embx(const int* __restrict__ dec_ids,
  const float* __restrict__ emb, const float* __restrict__ W_x,
  const float* __restrict__ Wpgen, u16* __restrict__ embx_bf, float* __restrict__ embxp){
  __shared__ float A[16][257];
  __shared__ int ids[16];
  __shared__ float red[8];
  const int tid = threadIdx.x, r0 = blockIdx.x*16;
  if (tid<16){
    int row = r0+tid, tt = row>>5, bb = row&31;
    ids[tid] = dec_ids[bb*Tq + tt];
  }
  __syncthreads();
  for (int idx=tid; idx<16*256; idx+=512){
    int rr = idx>>8, kk = idx&255;
    A[rr][kk] = emb[(size_t)ids[rr]*EMBq + kk];
  }
  __syncthreads();
  float acc[16];
  #pragma unroll
  for (int r=0;r<16;++r) acc[r]=0.f;
  for (int k=0;k<256;++k){
    float w = W_x[(size_t)k*HIDq + tid];
    #pragma unroll
    for (int r=0;r<16;++r) acc[r] += A[r][k]*w;
  }
  float wp4 = Wpgen[1536+tid];
  for (int r=0;r<16;++r){
    embx_bf[(size_t)(r0+r)*HIDq + tid] = f2bf(acc[r]);
    float s = blockSum512(acc[r]*wp4, red);
    if (tid==0) embxp[r0+r] = s;
  }
}

// ---- 32x32 transpose (f32) ----
__global__ __launch_bounds__(512) void k_trans(const float* __restrict__ in,
    float* __restrict__ out, int K, int N){
  __shared__ float T[32][33];
  const int n0 = blockIdx.x*32, k0 = blockIdx.y*32;
  const int tid = threadIdx.x;
  for (int idx=tid; idx<1024; idx+=512){
    int kk = idx>>5, nn = idx&31;
    T[kk][nn] = in[(size_t)(k0+kk)*N + n0+nn];
  }
  __syncthreads();
  for (int idx=tid; idx<1024; idx+=512){
    int nn = idx>>5, kk = idx&31;
    out[(size_t)(n0+nn)*K + k0+kk] = T[kk][nn];
  }
}

// ---- WGC: coalesced gate-weight layout ----
__global__ __launch_bounds__(512) void k_wgc(const float* __restrict__ WXKT_,
    const float* __restrict__ WrT_, u16* __restrict__ WGC){
  const int np = blockIdx.x;
  const int colg = np>>2, g = np&3;
  const int n = g*512 + colg;
  const float* s1 = WXKT_ + (size_t)n*512;
  const float* s2 = WrT_  + (size_t)n*512;
  const int sc = np>>8, npl = np&255;
  u16* o = WGC + (size_t)sc*262144 + (size_t)npl*8;
  const int k = threadIdx.x;
  o[(size_t)(k>>3)*2048 + (k&7)] = f2bf(s1[k]);
  const int k2 = k + 512;
  o[(size_t)(k2>>3)*2048 + (k2&7)] = f2bf(s2[k]);
}

// ==== persistent recurrence v9 (verified): 256 blocks x 1024 threads ====
__global__ __launch_bounds__(1024,1) void k_rec9(
  const u16* __restrict__ EFbf, const float* __restrict__ mask,
  const float* __restrict__ init_h, const float* __restrict__ init_c,
  const u16* __restrict__ WGC, const float* __restrict__ embz,
  const u16* __restrict__ WAbf, const float* __restrict__ vvec,
  const float* __restrict__ wcov, const float* __restrict__ bcov,
  const float* __restrict__ Wpgen, const float* __restrict__ Wxp,
  float* __restrict__ Hg, float* __restrict__ ctx_acc,
  float* __restrict__ df_acc, float* __restrict__ Z_acc,
  u16* __restrict__ hc_bf, float* __restrict__ attn_ws,
  float* __restrict__ pgen_raw, unsigned* __restrict__ msl)
{
  __shared__ float xA[1024];
  __shared__ float zl4[4][256];
  __shared__ float hsl[64], csl[64];
  __shared__ float covb[64], wsv[64], coldv[64];
  __shared__ float dfp[1024];
  __shared__ float dfl[512];
  __shared__ float ctp[1024];
  __shared__ float el[64];
  __shared__ float Zsh;

  const int tid = threadIdx.x, bid = blockIdx.x;
  const int lane = tid&63, wv = tid>>6;
  const int sc = bid & 7, bB = bid >> 3, s0 = sc*64;
  const int j0l = lane*8;
  unsigned* gs = msl + bB*16;

  float vvr[8], wcr[8], bcr[8];
  *(float4*)&vvr[0] = *(const float4*)&vvec[j0l]; *(float4*)&vvr[4] = *(const float4*)&vvec[j0l+4];
  *(float4*)&wcr[0] = *(const float4*)&wcov[j0l]; *(float4*)&wcr[4] = *(const float4*)&wcov[j0l+4];
  *(float4*)&bcr[0] = *(const float4*)&bcov[j0l]; *(float4*)&bcr[4] = *(const float4*)&bcov[j0l+4];

  if (tid<64) csl[tid] = init_c[bB*512 + s0 + tid];

  const int colL = tid & 255;
  const int kq = tid >> 8;
  const u16* wbase = WGC + (size_t)sc*262144 + (size_t)(kq*32)*2048 + (size_t)colL*8;
  const float* xs = &xA[kq*256];

  unsigned mt = 0;

  for (int t=0; t<Tq; ++t){
    //================= PHASE 1 =================
    if (t==0){
      if (tid<512) xA[tid] = 0.f;
      else xA[tid] = init_h[bB*512 + (tid-512)];
      if (tid<64) st1(ctx_acc + bB*512 + s0+tid, 0.f);
      if (tid==0 && sc==0) st1(Z_acc + bB, 0.f);
      __syncthreads();
    } else {
      const int pr = (t-1)&1;
      float2 cf, hf; float Zl = 0.f;
      if (tid<256) cf = ld2(ctx_acc + (size_t)pr*16384 + bB*512 + tid*2);
      else if (tid<512) hf = ld2(Hg + (size_t)pr*16384 + bB*512 + (tid-256)*2);
      if (tid==0)  Zl = ld1(Z_acc + pr*32 + bB);
      if (tid<64)  coldv[tid] = xA[s0+tid];
      if (tid==0)  Zsh = Zl;
      __syncthreads();
      const float Z = Zsh;
      if (tid<256){ xA[tid*2] = cf.x/Z; xA[tid*2+1] = cf.y/Z; }
      else if (tid<512){ xA[512+(tid-256)*2] = hf.x; xA[512+(tid-256)*2+1] = hf.y; }
      __syncthreads();
      if (tid<64){
        const int j = s0+tid;
        float cxj = xA[j];
        __builtin_nontemporal_store(f2bf(cxj), hc_bf + ((size_t)(t-1)*Bq+bB)*1024 + 512 + j);
        float a = wsv[tid]/Z;
        __builtin_nontemporal_store(a, attn_ws + ((size_t)(t-1)*Bq+bB)*Sq + j);
        covb[tid] = (t==1) ? a : covb[tid]+a;
        float part = cxj*Wpgen[j] + hsl[tid]*Wpgen[512+j]
                   + csl[tid]*Wpgen[1024+j] + coldv[tid]*Wxp[j];
        #pragma unroll
        for (int off=32; off>0; off>>=1) part += __shfl_down(part, off);
        if (tid==0) atadd(pgen_raw + (t-1)*Bq + bB, part);
      }
      if (tid<64) st1(ctx_acc + (size_t)(t&1)*16384 + bB*512 + s0+tid, 0.f);
      if (tid==0 && sc==0) st1(Z_acc + (t&1)*32 + bB, 0.f);
      __syncthreads();
    }
    // gate GEMV slice: 256 cols x 4 k-quarters
    {
      float acc = 0.f;
      #pragma unroll 8
      for (int kb=0; kb<32; ++kb){
        bf16x8 w8 = *(const bf16x8*)(wbase + (size_t)kb*2048);
        const u16* ph = (const u16*)&w8;
        float4 x0 = *(const float4*)(xs + kb*8);
        float4 x1 = *(const float4*)(xs + kb*8 + 4);
        acc += x0.x*bf2f(ph[0]) + x0.y*bf2f(ph[1]) + x0.z*bf2f(ph[2]) + x0.w*bf2f(ph[3])
             + x1.x*bf2f(ph[4]) + x1.y*bf2f(ph[5]) + x1.z*bf2f(ph[6]) + x1.w*bf2f(ph[7]);
      }
      zl4[kq][colL] = acc;
    }
    __syncthreads();
    // LSTM own 64 cols
    if (tid<64){
      const int colg = s0 + tid;
      const float* ez = embz + ((size_t)t*Bq + bB)*2048 + colg;
      float zi = (zl4[0][tid*4+0]+zl4[1][tid*4+0])+(zl4[2][tid*4+0]+zl4[3][tid*4+0])
               + __builtin_nontemporal_load(ez);
      float zf = (zl4[0][tid*4+1]+zl4[1][tid*4+1])+(zl4[2][tid*4+1]+zl4[3][tid*4+1])
               + __builtin_nontemporal_load(ez+512);
      float zg = (zl4[0][tid*4+2]+zl4[1][tid*4+2])+(zl4[2][tid*4+2]+zl4[3][tid*4+2])
               + __builtin_nontemporal_load(ez+1024);
      float zo = (zl4[0][tid*4+3]+zl4[1][tid*4+3])+(zl4[2][tid*4+3]+zl4[3][tid*4+3])
               + __builtin_nontemporal_load(ez+1536);
      float co = csl[tid];
      float cn = sigmoidf_(zf)*co + sigmoidf_(zi)*tanhf_(zg);
      float hn = sigmoidf_(zo)*tanhf_(cn);
      csl[tid] = cn;
      hsl[tid] = hn;
      st1(Hg + (size_t)(t&1)*16384 + bB*512 + colg, hn);
      __builtin_nontemporal_store(f2bf(hn), hc_bf + ((size_t)t*Bq+bB)*1024 + colg);
    }
    __syncthreads();
    // df k-partial over own h/c slice
    {
      const int j = tid & 511, half = tid >> 9;
      const float* st = half ? csl : hsl;
      const u16* wa = WAbf + (size_t)(half*512 + s0)*512 + j;
      float acc = 0.f;
      #pragma unroll 8
      for (int k=0;k<64;++k) acc += st[k]*bf2f(wa[(size_t)k*512]);
      dfp[tid] = acc;
    }
    __syncthreads();
    if (tid<512) atadd(df_acc + (size_t)(t&1)*16384 + bB*512 + tid, dfp[tid]+dfp[512+tid]);
    ++mt; mbar(gs, sc, mt);
    //================= PHASE 2 =================
    if (tid<256){
      float2 f = ld2(df_acc + (size_t)(t&1)*16384 + bB*512 + tid*2);
      dfl[tid*2]=f.x; dfl[tid*2+1]=f.y;
    } else if (tid>=960){
      st1(df_acc + (size_t)((t+1)&1)*16384 + bB*512 + s0 + (tid-960), 0.f);
    }
    __syncthreads();
    // e-pass: 16 waves x 4 s-rows
    {
      float dd[8];
      *(float4*)&dd[0] = *(const float4*)&dfl[j0l];
      *(float4*)&dd[4] = *(const float4*)&dfl[j0l+4];
      const u16* efb = EFbf + ((size_t)(bB*512 + s0))*512;
      #pragma unroll
      for (int r=0;r<4;++r){
        int sl = wv*4 + r;
        uint4 pack = *(const uint4*)(efb + (size_t)sl*512 + j0l);
        const u16* ph = (const u16*)&pack;
        float a8 = 0.f;
        if (t>0){
          float cvs = covb[sl];
          #pragma unroll
          for (int q=0;q<8;++q) a8 += vvr[q]*tanhf_(bf2f(ph[q])+dd[q]+cvs*wcr[q]+bcr[q]);
        } else {
          #pragma unroll
          for (int q=0;q<8;++q) a8 += vvr[q]*tanhf_(bf2f(ph[q])+dd[q]);
        }
        #pragma unroll
        for (int off=32; off>0; off>>=1) a8 += __shfl_down(a8, off);
        if (lane==0) el[sl] = a8;
      }
    }
    __syncthreads();
    // no-max weights + Z atomic
    if (tid<64){
      float w_ = mask[bB*512+s0+tid]*__expf(el[tid]);
      wsv[tid] = w_;
      float Zc = w_;
      #pragma unroll
      for (int off=32; off>0; off>>=1) Zc += __shfl_xor(Zc, off);
      if (tid==0) atadd(Z_acc + (t&1)*32 + bB, Zc);
    }
    __syncthreads();
    // ctx partial
    {
      const int j = tid & 511, sh = tid >> 9;
      const u16* efc = EFbf + ((size_t)(bB*512 + s0 + sh*32))*512 + j;
      float acc = 0.f;
      #pragma unroll 4
      for (int s=0;s<32;++s) acc += wsv[sh*32+s]*bf2f(efc[(size_t)s*512]);
      ctp[tid] = acc;
    }
    __syncthreads();
    if (tid<512) atadd(ctx_acc + (size_t)(t&1)*16384 + bB*512 + tid, ctp[tid]+ctp[512+tid]);
    ++mt; mbar(gs, sc, mt);
  }
  //================= epilogue =================
  {
    const int pr = (Tq-1)&1;
    float2 cf; float Zl = 0.f;
    if (tid<256) cf = ld2(ctx_acc + (size_t)pr*16384 + bB*512 + tid*2);
    if (tid==0)  Zl = ld1(Z_acc + pr*32 + bB);
    if (tid<64)  coldv[tid] = xA[s0+tid];
    if (tid==0)  Zsh = Zl;
    __syncthreads();
    const float Z = Zsh;
    if (tid<256){ xA[tid*2] = cf.x/Z; xA[tid*2+1] = cf.y/Z; }
    __syncthreads();
    if (tid<64){
      const int j = s0+tid;
      float cxj = xA[j];
      __builtin_nontemporal_store(f2bf(cxj), hc_bf + ((size_t)(Tq-1)*Bq+bB)*1024 + 512 + j);
      float a = wsv[tid]/Z;
      __builtin_nontemporal_store(a, attn_ws + ((size_t)(Tq-1)*Bq+bB)*Sq + j);
      float part = cxj*Wpgen[j] + hsl[tid]*Wpgen[512+j]
                 + csl[tid]*Wpgen[1024+j] + coldv[tid]*Wxp[j];
      #pragma unroll
      for (int off=32; off>0; off>>=1) part += __shfl_down(part, off);
      if (tid==0) atadd(pgen_raw + (Tq-1)*Bq + bB, part);
    }
  }
}

// ---- probs_un = exp(Abf @ W_proj + b_proj), direct f32 B with LDS transpose ----
// grid (8, 391): x = m-tile (fast; same-n blocks share B tile in L2)
__global__ __launch_bounds__(256) void k_projsf(const u16* __restrict__ Abf,
    const float* __restrict__ Wp, const float* __restrict__ b_proj,
    float* __restrict__ out, float* __restrict__ rowsum){
  __shared__ u16 As[128*40];
  __shared__ u16 Bs[128*40];
  const int tid = threadIdx.x;
  const int m0 = blockIdx.x * 128;
  const int n0 = blockIdx.y * 128;
  const int wid = tid>>6, lane = tid&63;
  const int wm = (wid>>1)*64, wn = (wid&1)*64;
  const int l15 = lane&15, l4 = lane>>4;
  f32x4 acc[4][4];
  #pragma unroll
  for (int mi=0;mi<4;++mi)
    #pragma unroll
    for (int ni=0;ni<4;++ni) acc[mi][ni] = (f32x4){0.f,0.f,0.f,0.f};

  for (int kt=0; kt<16; ++kt){
    const int k0 = kt*32;
    __syncthreads();
    #pragma unroll
    for (int it=0; it<2; ++it){
      int id = tid + it*256;
      int row = id>>2, c4 = id&3;
      uint4 va = *(const uint4*)(Abf + (size_t)(m0+row)*512 + k0 + c4*8);
      *(uint4*)(&As[row*40 + c4*8]) = va;
    }
    // B: read W_proj[k0+kk][n0+nn] f32 (coalesced rows), transpose to Bs[nn][kk]
    #pragma unroll
    for (int it=0; it<4; ++it){
      int id = tid + it*256;          // 0..1023
      int kk = id>>5;                 // 0..31
      int nn4 = (id&31)*4;            // 0..124
      int gn = n0 + nn4;
      const float* src = Wp + (size_t)(k0+kk)*VOCABq + gn;
      float4 v;
      if (gn+3 < VOCABq) v = *(const float4*)src;
      else {
        v.x = (gn+0<VOCABq)? src[0] : 0.f;
        v.y = (gn+1<VOCABq)? src[1] : 0.f;
        v.z = (gn+2<VOCABq)? src[2] : 0.f;
        v.w = (gn+3<VOCABq)? src[3] : 0.f;
      }
      Bs[(nn4+0)*40 + kk] = f2bf(v.x);
      Bs[(nn4+1)*40 + kk] = f2bf(v.y);
      Bs[(nn4+2)*40 + kk] = f2bf(v.z);
      Bs[(nn4+3)*40 + kk] = f2bf(v.w);
    }
    __syncthreads();
    bf16x8 a[4], b[4];
    #pragma unroll
    for (int mi=0;mi<4;++mi)
      a[mi] = *(const bf16x8*)(&As[(wm + mi*16 + l15)*40 + l4*8]);
    #pragma unroll
    for (int ni=0;ni<4;++ni)
      b[ni] = *(const bf16x8*)(&Bs[(wn + ni*16 + l15)*40 + l4*8]);
    #pragma unroll
    for (int mi=0;mi<4;++mi)
      #pragma unroll
      for (int ni=0;ni<4;++ni)
        acc[mi][ni] = __builtin_amdgcn_mfma_f32_16x16x32_bf16(a[mi], b[ni], acc[mi][ni], 0,0,0);
  }

  float prow[4][4];
  #pragma unroll
  for (int mi=0;mi<4;++mi)
    #pragma unroll
    for (int r=0;r<4;++r) prow[mi][r]=0.f;

  #pragma unroll
  for (int ni=0;ni<4;++ni){
    const int col = n0 + wn + ni*16 + l15;
    const bool ok = (col < VOCABq);
    const float bp = ok ? b_proj[col] : 0.f;
    #pragma unroll
    for (int mi=0;mi<4;++mi){
      const int rbase = m0 + wm + mi*16 + l4*4;
      #pragma unroll
      for (int r=0;r<4;++r){
        float p = ok ? __expf(acc[mi][ni][r] + bp) : 0.f;
        if (ok) out[(size_t)(rbase+r)*VEXTq + col] = p;
        prow[mi][r] += p;
      }
    }
  }
  #pragma unroll
  for (int mi=0;mi<4;++mi)
    #pragma unroll
    for (int r=0;r<4;++r){
      float v = prow[mi][r];
      v += __shfl_xor(v,1); v += __shfl_xor(v,2);
      v += __shfl_xor(v,4); v += __shfl_xor(v,8);
      if (l15==0) atadd(rowsum + m0 + wm + mi*16 + l4*4 + r, v);
    }
}

// ---- single-pass finalize (float4): scale, zero OOV, scatter ----
__global__ __launch_bounds__(256) void k_sm2(float* __restrict__ out,
    const float* __restrict__ rowsum, const float* __restrict__ pgen_raw,
    const float* __restrict__ embxp, const float* __restrict__ attn_ws,
    const int* __restrict__ enc_ids){
  const int row=blockIdx.x, tid=threadIdx.x;
  const int b = row & (Bq-1);
  float* orow = out + (size_t)row*VEXTq;
  const float pg = sigmoidf_(pgen_raw[row] + embxp[row]);
  const float scale = pg / rowsum[row];
  float4* o4 = (float4*)orow;
  for (int i=tid;i<VOCABq/4;i+=256){
    float4 v = o4[i];
    v.x*=scale; v.y*=scale; v.z*=scale; v.w*=scale;
    o4[i] = v;
  }
  for (int i=VOCABq+tid;i<VEXTq;i+=256) orow[i] = 0.f;
  __syncthreads();
  const float w1 = 1.f-pg;
  const float* arow = attn_ws + (size_t)row*Sq;
  const int* ids = enc_ids + b*Sq;
  for (int si=tid; si<Sq; si+=256)
    atomicAdd(&orow[ids[si]], w1*arow[si]);
}

extern "C" void kernel_launch(void* const* d_in, const int* in_sizes, int n_in,
                              void* d_out, int out_size, void* d_ws, size_t ws_size,
                              hipStream_t stream) {
  (void)in_sizes; (void)n_in; (void)out_size; (void)ws_size;
  const int*   dec_ids    = (const int*)  d_in[0];
  const int*   enc_ids    = (const int*)  d_in[1];
  const float* enc_states = (const float*)d_in[2];
  const float* mask       = (const float*)d_in[3];
  const float* init_h     = (const float*)d_in[4];
  const float* init_c     = (const float*)d_in[5];
  const float* embeddings = (const float*)d_in[6];
  const float* W_enc      = (const float*)d_in[7];
  const float* b_enc      = (const float*)d_in[8];
  const float* W_attn     = (const float*)d_in[9];
  const float* vvec       = (const float*)d_in[10];
  const float* w_cov      = (const float*)d_in[11];
  const float* b_cov      = (const float*)d_in[12];
  const float* W_x        = (const float*)d_in[13];
  const float* W_out      = (const float*)d_in[14];
  const float* Wk         = (const float*)d_in[15];
  const float* Wr         = (const float*)d_in[16];
  const float* b_lstm     = (const float*)d_in[17];
  const float* W_pgen     = (const float*)d_in[18];
  const float* W_proj     = (const float*)d_in[19];
  const float* b_proj     = (const float*)d_in[20];
  float* out = (float*)d_out;
  float* ws  = (float*)d_ws;

  u16*   EFbf    = (u16*)ws;
  float* attn_ws = ws + 4194304;
  u16*   hc_bf   = (u16*)(attn_ws + 524288);
  u16*   outm_bf = (u16*)(attn_ws + 524288 + 524288);
  u16*   embx_bf = (u16*)(attn_ws + 524288 + 524288 + 262144);
  float* embxp   = attn_ws + 524288 + 524288 + 262144 + 262144;
  float* embz    = embxp + 1024;
  float* WXKT_   = embz + 2097152;
  float* WrT_    = WXKT_ + 1048576;
  u16*   WkT     = (u16*)(WrT_ + 1048576);
  u16*   Xb      = (u16*)(((float*)WkT) + 524288);
  u16*   WoT     = (u16*)(((float*)Xb) + 131072);
  float* Wxp     = ((float*)WoT) + 262144;
  float* Hg      = Wxp + 512;
  unsigned* msl  = (unsigned*)(Hg + 32768);
  float* pgen_raw= (float*)(msl + 512);
  float* ctx_acc = pgen_raw + 1024;
  float* df_acc  = ctx_acc + 32768;
  float* Z_acc   = df_acc + 32768;
  float* rowsum  = Z_acc + 64;
  u16*   WGC     = (u16*)(rowsum + 1024);
  u16*   WAbf    = (u16*)(((float*)WGC) + 1048576);
  u16*   WET     = (u16*)(((float*)WAbf) + 262144);

  hipMemsetAsync(msl, 0, (512 + 1024 + 32768 + 32768 + 64 + 1024)*sizeof(unsigned), stream);

  // ---- precompute ----
  k_prep<<<3840, 256, 0, stream>>>(W_enc, WET, Wk, WkT, W_out, WoT, W_attn, WAbf);
  {
    dim3 g(128,4);
    k_encm<<<g, 256, 0, stream>>>(enc_states, WET, b_enc, EFbf);
  }
  k_embx<<<64, 512, 0, stream>>>(dec_ids, embeddings, W_x, W_pgen, embx_bf, embxp);
  k_wx2c<<<512, 512, 0, stream>>>(W_x, W_pgen, Xb, Wxp);
  {
    dim3 g(8,16);
    k_gemm512<<<g, 256, 0, stream>>>(embx_bf, WkT, b_lstm, embz, 2048, 1);
  }
  {
    dim3 g(16,4);
    k_gemm512<<<g, 256, 0, stream>>>(WkT, Xb, (const float*)0, WXKT_, 512, 0);
  }
  {
    dim3 g(64,16);
    k_trans<<<g, 512, 0, stream>>>(Wr, WrT_, 512, 2048);
  }
  k_wgc<<<2048, 512, 0, stream>>>(WXKT_, WrT_, WGC);

  // ---- recurrence: 256 blocks x 1024 threads (verified structure) ----
  {
    void* args[] = { (void*)&EFbf, (void*)&mask, (void*)&init_h, (void*)&init_c,
                     (void*)&WGC, (void*)&embz, (void*)&WAbf, (void*)&vvec,
                     (void*)&w_cov, (void*)&b_cov, (void*)&W_pgen, (void*)&Wxp,
                     (void*)&Hg, (void*)&ctx_acc, (void*)&df_acc, (void*)&Z_acc,
                     (void*)&hc_bf, (void*)&attn_ws, (void*)&pgen_raw,
                     (void*)&msl };
    hipLaunchCooperativeKernel((void*)k_rec9, dim3(256), dim3(1024), args, 0, stream);
  }

  // ---- output projection (MFMA mid + direct-f32 proj) + finalize ----
  {
    dim3 g(8,4);
    k_gemmb<<<g, 256, 0, stream>>>(hc_bf, WoT, outm_bf, 1024, 512);
  }
  {
    dim3 gp(8, 391);
    k_projsf<<<gp, 256, 0, stream>>>(outm_bf, W_proj, b_proj, out, rowsum);
  }
  k_sm2<<<Tq*Bq, 256, 0, stream>>>(out, rowsum, pgen_raw, embxp, attn_ws, enc_ids);
}

// Round 16
// 1390.949 us; speedup vs baseline: 1.0749x; 1.0749x over previous
//
#include <hip/hip_runtime.h>
#include <math.h>

#define Bq 32
#define Sq 512
#define Tq 32
#define EMBq 256
#define HIDq 512
#define VOCABq 50000
#define OOVq 100
#define VEXTq (VOCABq + OOVq)
#define FULL_N 50176

typedef unsigned short u16;
typedef unsigned long long u64;
typedef __attribute__((ext_vector_type(8))) short bf16x8;
typedef __attribute__((ext_vector_type(4))) float f32x4;

__device__ __forceinline__ float sigmoidf_(float x){ return 1.0f/(1.0f+__expf(-x)); }
__device__ __forceinline__ float tanhf_(float x){ return 1.0f - 2.0f/(__expf(2.0f*x)+1.0f); }

__device__ __forceinline__ u16 f2bf(float x){
  union{float f; unsigned u;} v; v.f=x;
  unsigned r = v.u + 0x7FFFu + ((v.u>>16)&1u);
  return (u16)(r>>16);
}
__device__ __forceinline__ float bf2f(u16 h){
  union{unsigned u; float f;} v; v.u = ((unsigned)h)<<16; return v.f;
}

// ---- agent-scope (L2-bypass, device-coherent) accessors ----
__device__ __forceinline__ float ld1(const float* p){
  return __hip_atomic_load((float*)p, __ATOMIC_RELAXED, __HIP_MEMORY_SCOPE_AGENT);
}
__device__ __forceinline__ void st1(float* p, float v){
  __hip_atomic_store(p, v, __ATOMIC_RELAXED, __HIP_MEMORY_SCOPE_AGENT);
}
__device__ __forceinline__ float2 ld2(const float* p){
  u64 v = __hip_atomic_load((u64*)p, __ATOMIC_RELAXED, __HIP_MEMORY_SCOPE_AGENT);
  union{u64 u; float2 f;} c; c.u=v; return c.f;
}
__device__ __forceinline__ void atadd(float* p, float v){
  __hip_atomic_fetch_add(p, v, __ATOMIC_RELAXED, __HIP_MEMORY_SCOPE_AGENT);
}

// ---- group-local barrier: 8 blocks, distributed slots ----
__device__ __forceinline__ void mbar(unsigned* gs, int sc, unsigned tag){
  asm volatile("s_waitcnt vmcnt(0)" ::: "memory");
  __syncthreads();
  if (threadIdx.x==0)
    __hip_atomic_store(gs+sc, tag, __ATOMIC_RELAXED, __HIP_MEMORY_SCOPE_AGENT);
  if (threadIdx.x<64){
    for(;;){
      unsigned v = (threadIdx.x<8)
        ? __hip_atomic_load(gs+threadIdx.x, __ATOMIC_RELAXED, __HIP_MEMORY_SCOPE_AGENT)
        : tag;
      if (__all(v>=tag)) break;
      __builtin_amdgcn_s_sleep(1);
    }
  }
  __syncthreads();
}

__device__ __forceinline__ float blockSum512(float v, float* red){
  #pragma unroll
  for (int off=32; off>0; off>>=1) v += __shfl_down(v, off);
  int lane = threadIdx.x & 63, wid = threadIdx.x >> 6;
  __syncthreads();
  if (lane==0) red[wid]=v;
  __syncthreads();
  float t=0.f;
  #pragma unroll
  for (int w=0;w<8;++w) t+=red[w];
  return t;
}

// ---- merged prep: WET/WkT/WoT transposes + WAbf convert ----
__global__ __launch_bounds__(256) void k_prep(
    const float* __restrict__ W_enc, u16* __restrict__ WET,
    const float* __restrict__ Wk,    u16* __restrict__ WkT,
    const float* __restrict__ W_out, u16* __restrict__ WoT,
    const float* __restrict__ W_attn,u16* __restrict__ WAbf){
  __shared__ float T[32][33];
  const int bid = blockIdx.x, tid = threadIdx.x;
  if (bid < 1792){
    const float* in; u16* out; int ldin, ldout, n0, k0;
    if (bid < 256){ in=W_enc; out=WET; ldin=512; ldout=512;
      n0=(bid&15)*32; k0=(bid>>4)*32; }
    else if (bid < 1280){ int b=bid-256; in=Wk; out=WkT; ldin=2048; ldout=512;
      n0=(b&63)*32; k0=(b>>6)*32; }
    else { int b=bid-1280; in=W_out; out=WoT; ldin=512; ldout=1024;
      n0=(b&15)*32; k0=(b>>4)*32; }
    #pragma unroll
    for (int it=0; it<4; ++it){
      int id=tid+it*256; int kk=id>>5, nn=id&31;
      T[kk][nn] = in[(size_t)(k0+kk)*ldin + n0+nn];
    }
    __syncthreads();
    #pragma unroll
    for (int it=0; it<4; ++it){
      int id=tid+it*256; int nn=id>>5, kk=id&31;
      out[(size_t)(n0+nn)*ldout + k0+kk] = f2bf(T[kk][nn]);
    }
  } else {
    int i = (bid-1792)*256 + tid;
    WAbf[i] = f2bf(W_attn[i]);
  }
}

// ---- Xb[j][i] = bf16(W_x[256+j][i]); Wxp[j] = sum_i W_x[256+j][i]*Wpgen[1536+i] ----
__global__ __launch_bounds__(512) void k_wx2c(const float* __restrict__ W_x,
    const float* __restrict__ Wpgen, u16* __restrict__ Xb, float* __restrict__ Wxp){
  __shared__ float red[8];
  const int j = blockIdx.x, i = threadIdx.x;
  float v = W_x[(size_t)(256+j)*512 + i];
  Xb[(size_t)j*512 + i] = f2bf(v);
  float s = blockSum512(v*Wpgen[1536+i], red);
  if (i==0) Wxp[j] = s;
}

// ---- generic MFMA GEMM (K=512): out f32 [M][ncols] = A@B^T (+bias) ----
__global__ __launch_bounds__(256) void k_gemm512(const u16* __restrict__ A,
    const u16* __restrict__ B, const float* __restrict__ bias,
    float* __restrict__ out, int ncols, int use_bias){
  __shared__ u16 As[128*40];
  __shared__ u16 Bs[128*40];
  const int tid = threadIdx.x;
  const int m0 = blockIdx.x * 128;
  const int n0 = blockIdx.y * 128;
  const int wid = tid>>6, lane = tid&63;
  const int wm = (wid>>1)*64, wn = (wid&1)*64;
  const int l15 = lane&15, l4 = lane>>4;
  f32x4 acc[4][4];
  #pragma unroll
  for (int mi=0;mi<4;++mi)
    #pragma unroll
    for (int ni=0;ni<4;++ni) acc[mi][ni] = (f32x4){0.f,0.f,0.f,0.f};
  for (int kt=0; kt<16; ++kt){
    const int k0 = kt*32;
    __syncthreads();
    #pragma unroll
    for (int it=0; it<2; ++it){
      int id = tid + it*256;
      int row = id>>2, c4 = id&3;
      uint4 va = *(const uint4*)(A + (size_t)(m0+row)*512 + k0 + c4*8);
      *(uint4*)(&As[row*40 + c4*8]) = va;
      uint4 vb = *(const uint4*)(B + (size_t)(n0+row)*512 + k0 + c4*8);
      *(uint4*)(&Bs[row*40 + c4*8]) = vb;
    }
    __syncthreads();
    bf16x8 a[4], b[4];
    #pragma unroll
    for (int mi=0;mi<4;++mi) a[mi] = *(const bf16x8*)(&As[(wm+mi*16+l15)*40 + l4*8]);
    #pragma unroll
    for (int ni=0;ni<4;++ni) b[ni] = *(const bf16x8*)(&Bs[(wn+ni*16+l15)*40 + l4*8]);
    #pragma unroll
    for (int mi=0;mi<4;++mi)
      #pragma unroll
      for (int ni=0;ni<4;++ni)
        acc[mi][ni] = __builtin_amdgcn_mfma_f32_16x16x32_bf16(a[mi], b[ni], acc[mi][ni], 0,0,0);
  }
  #pragma unroll
  for (int ni=0;ni<4;++ni){
    const int col = n0 + wn + ni*16 + l15;
    const float bp = use_bias ? bias[col] : 0.f;
    #pragma unroll
    for (int mi=0;mi<4;++mi){
      const int rbase = m0 + wm + mi*16 + l4*4;
      #pragma unroll
      for (int r=0;r<4;++r)
        out[(size_t)(rbase+r)*ncols + col] = acc[mi][ni][r] + bp;
    }
  }
}

// ---- generic-K MFMA GEMM, bf16 out ----
__global__ __launch_bounds__(256) void k_gemmb(const u16* __restrict__ A,
    const u16* __restrict__ B, u16* __restrict__ out, int K, int N){
  __shared__ u16 As[128*40];
  __shared__ u16 Bs[128*40];
  const int tid = threadIdx.x;
  const int m0 = blockIdx.x * 128;
  const int n0 = blockIdx.y * 128;
  const int wid = tid>>6, lane = tid&63;
  const int wm = (wid>>1)*64, wn = (wid&1)*64;
  const int l15 = lane&15, l4 = lane>>4;
  f32x4 acc[4][4];
  #pragma unroll
  for (int mi=0;mi<4;++mi)
    #pragma unroll
    for (int ni=0;ni<4;++ni) acc[mi][ni] = (f32x4){0.f,0.f,0.f,0.f};
  const int kts = K>>5;
  for (int kt=0; kt<kts; ++kt){
    const int k0 = kt*32;
    __syncthreads();
    #pragma unroll
    for (int it=0; it<2; ++it){
      int id = tid + it*256;
      int row = id>>2, c4 = id&3;
      uint4 va = *(const uint4*)(A + (size_t)(m0+row)*K + k0 + c4*8);
      *(uint4*)(&As[row*40 + c4*8]) = va;
      uint4 vb = *(const uint4*)(B + (size_t)(n0+row)*K + k0 + c4*8);
      *(uint4*)(&Bs[row*40 + c4*8]) = vb;
    }
    __syncthreads();
    bf16x8 a[4], b[4];
    #pragma unroll
    for (int mi=0;mi<4;++mi) a[mi] = *(const bf16x8*)(&As[(wm+mi*16+l15)*40 + l4*8]);
    #pragma unroll
    for (int ni=0;ni<4;++ni) b[ni] = *(const bf16x8*)(&Bs[(wn+ni*16+l15)*40 + l4*8]);
    #pragma unroll
    for (int mi=0;mi<4;++mi)
      #pragma unroll
      for (int ni=0;ni<4;++ni)
        acc[mi][ni] = __builtin_amdgcn_mfma_f32_16x16x32_bf16(a[mi], b[ni], acc[mi][ni], 0,0,0);
  }
  #pragma unroll
  for (int ni=0;ni<4;++ni){
    const int col = n0 + wn + ni*16 + l15;
    #pragma unroll
    for (int mi=0;mi<4;++mi){
      const int rbase = m0 + wm + mi*16 + l4*4;
      #pragma unroll
      for (int r=0;r<4;++r)
        out[(size_t)(rbase+r)*N + col] = f2bf(acc[mi][ni][r]);
    }
  }
}

// ---- EFbf = bf16( es @ W_enc + b_enc ), MFMA ----
__global__ __launch_bounds__(256) void k_encm(const float* __restrict__ es,
    const u16* __restrict__ WET, const float* __restrict__ b_enc,
    u16* __restrict__ EFbf){
  __shared__ u16 As[128*40];
  __shared__ u16 Bs[128*40];
  const int tid=threadIdx.x;
  const int m0 = blockIdx.x*128, n0 = blockIdx.y*128;
  const int wid=tid>>6, lane=tid&63;
  const int wm=(wid>>1)*64, wn=(wid&1)*64;
  const int l15=lane&15, l4=lane>>4;
  f32x4 acc[4][4];
  #pragma unroll
  for (int mi=0;mi<4;++mi)
    #pragma unroll
    for (int ni=0;ni<4;++ni) acc[mi][ni] = (f32x4){0.f,0.f,0.f,0.f};
  for (int kt=0; kt<16; ++kt){
    const int k0=kt*32;
    __syncthreads();
    #pragma unroll
    for (int it=0; it<4; ++it){
      int id=tid+it*256; int row=id>>3, q=id&7;
      float4 v = *(const float4*)(es + (size_t)(m0+row)*512 + k0 + q*4);
      u64 pk = (u64)f2bf(v.x) | ((u64)f2bf(v.y)<<16) | ((u64)f2bf(v.z)<<32) | ((u64)f2bf(v.w)<<48);
      *(u64*)&As[row*40 + q*4] = pk;
    }
    #pragma unroll
    for (int it=0; it<2; ++it){
      int id=tid+it*256; int row=id>>2, c4=id&3;
      uint4 v = *(const uint4*)(WET + (size_t)(n0+row)*512 + k0 + c4*8);
      *(uint4*)&Bs[row*40 + c4*8] = v;
    }
    __syncthreads();
    bf16x8 a[4], b[4];
    #pragma unroll
    for (int mi=0;mi<4;++mi) a[mi] = *(const bf16x8*)(&As[(wm+mi*16+l15)*40 + l4*8]);
    #pragma unroll
    for (int ni=0;ni<4;++ni) b[ni] = *(const bf16x8*)(&Bs[(wn+ni*16+l15)*40 + l4*8]);
    #pragma unroll
    for (int mi=0;mi<4;++mi)
      #pragma unroll
      for (int ni=0;ni<4;++ni)
        acc[mi][ni] = __builtin_amdgcn_mfma_f32_16x16x32_bf16(a[mi], b[ni], acc[mi][ni], 0,0,0);
  }
  #pragma unroll
  for (int ni=0;ni<4;++ni){
    const int col = n0+wn+ni*16+l15;
    const float bp = b_enc[col];
    #pragma unroll
    for (int mi=0;mi<4;++mi){
      const int rb = m0+wm+mi*16+l4*4;
      #pragma unroll
      for (int r=0;r<4;++r)
        EFbf[(size_t)(rb+r)*512 + col] = f2bf(acc[mi][ni][r]+bp);
    }
  }
}

// ---- embx_bf (bf16) + embxp ----
__global__ __launch_bounds__(512) void k_embx(const int* __restrict__ dec_ids,
  const float* __restrict__ emb, const float* __restrict__ W_x,
  const float* __restrict__ Wpgen, u16* __restrict__ embx_bf, float* __restrict__ embxp){
  __shared__ float A[16][257];
  __shared__ int ids[16];
  __shared__ float red[8];
  const int tid = threadIdx.x, r0 = blockIdx.x*16;
  if (tid<16){
    int row = r0+tid, tt = row>>5, bb = row&31;
    ids[tid] = dec_ids[bb*Tq + tt];
  }
  __syncthreads();
  for (int idx=tid; idx<16*256; idx+=512){
    int rr = idx>>8, kk = idx&255;
    A[rr][kk] = emb[(size_t)ids[rr]*EMBq + kk];
  }
  __syncthreads();
  float acc[16];
  #pragma unroll
  for (int r=0;r<16;++r) acc[r]=0.f;
  for (int k=0;k<256;++k){
    float w = W_x[(size_t)k*HIDq + tid];
    #pragma unroll
    for (int r=0;r<16;++r) acc[r] += A[r][k]*w;
  }
  float wp4 = Wpgen[1536+tid];
  for (int r=0;r<16;++r){
    embx_bf[(size_t)(r0+r)*HIDq + tid] = f2bf(acc[r]);
    float s = blockSum512(acc[r]*wp4, red);
    if (tid==0) embxp[r0+r] = s;
  }
}

// ---- 32x32 transpose (f32) ----
__global__ __launch_bounds__(512) void k_trans(const float* __restrict__ in,
    float* __restrict__ out, int K, int N){
  __shared__ float T[32][33];
  const int n0 = blockIdx.x*32, k0 = blockIdx.y*32;
  const int tid = threadIdx.x;
  for (int idx=tid; idx<1024; idx+=512){
    int kk = idx>>5, nn = idx&31;
    T[kk][nn] = in[(size_t)(k0+kk)*N + n0+nn];
  }
  __syncthreads();
  for (int idx=tid; idx<1024; idx+=512){
    int nn = idx>>5, kk = idx&31;
    out[(size_t)(n0+nn)*K + k0+kk] = T[kk][nn];
  }
}

// ---- WGC: coalesced gate-weight layout ----
__global__ __launch_bounds__(512) void k_wgc(const float* __restrict__ WXKT_,
    const float* __restrict__ WrT_, u16* __restrict__ WGC){
  const int np = blockIdx.x;
  const int colg = np>>2, g = np&3;
  const int n = g*512 + colg;
  const float* s1 = WXKT_ + (size_t)n*512;
  const float* s2 = WrT_  + (size_t)n*512;
  const int sc = np>>8, npl = np&255;
  u16* o = WGC + (size_t)sc*262144 + (size_t)npl*8;
  const int k = threadIdx.x;
  o[(size_t)(k>>3)*2048 + (k&7)] = f2bf(s1[k]);
  const int k2 = k + 512;
  o[(size_t)(k2>>3)*2048 + (k2&7)] = f2bf(s2[k]);
}

// ==== persistent recurrence v9 (verified): 256 blocks x 1024 threads ====
__global__ __launch_bounds__(1024,1) void k_rec9(
  const u16* __restrict__ EFbf, const float* __restrict__ mask,
  const float* __restrict__ init_h, const float* __restrict__ init_c,
  const u16* __restrict__ WGC, const float* __restrict__ embz,
  const u16* __restrict__ WAbf, const float* __restrict__ vvec,
  const float* __restrict__ wcov, const float* __restrict__ bcov,
  const float* __restrict__ Wpgen, const float* __restrict__ Wxp,
  float* __restrict__ Hg, float* __restrict__ ctx_acc,
  float* __restrict__ df_acc, float* __restrict__ Z_acc,
  u16* __restrict__ hc_bf, float* __restrict__ attn_ws,
  float* __restrict__ pgen_raw, unsigned* __restrict__ msl)
{
  __shared__ float xA[1024];
  __shared__ float zl4[4][256];
  __shared__ float hsl[64], csl[64];
  __shared__ float covb[64], wsv[64], coldv[64];
  __shared__ float dfp[1024];
  __shared__ float dfl[512];
  __shared__ float ctp[1024];
  __shared__ float el[64];
  __shared__ float Zsh;

  const int tid = threadIdx.x, bid = blockIdx.x;
  const int lane = tid&63, wv = tid>>6;
  const int sc = bid & 7, bB = bid >> 3, s0 = sc*64;
  const int j0l = lane*8;
  unsigned* gs = msl + bB*16;

  float vvr[8], wcr[8], bcr[8];
  *(float4*)&vvr[0] = *(const float4*)&vvec[j0l]; *(float4*)&vvr[4] = *(const float4*)&vvec[j0l+4];
  *(float4*)&wcr[0] = *(const float4*)&wcov[j0l]; *(float4*)&wcr[4] = *(const float4*)&wcov[j0l+4];
  *(float4*)&bcr[0] = *(const float4*)&bcov[j0l]; *(float4*)&bcr[4] = *(const float4*)&bcov[j0l+4];

  if (tid<64) csl[tid] = init_c[bB*512 + s0 + tid];

  const int colL = tid & 255;
  const int kq = tid >> 8;
  const u16* wbase = WGC + (size_t)sc*262144 + (size_t)(kq*32)*2048 + (size_t)colL*8;
  const float* xs = &xA[kq*256];

  unsigned mt = 0;

  for (int t=0; t<Tq; ++t){
    //================= PHASE 1 =================
    if (t==0){
      if (tid<512) xA[tid] = 0.f;
      else xA[tid] = init_h[bB*512 + (tid-512)];
      if (tid<64) st1(ctx_acc + bB*512 + s0+tid, 0.f);
      if (tid==0 && sc==0) st1(Z_acc + bB, 0.f);
      __syncthreads();
    } else {
      const int pr = (t-1)&1;
      float2 cf, hf; float Zl = 0.f;
      if (tid<256) cf = ld2(ctx_acc + (size_t)pr*16384 + bB*512 + tid*2);
      else if (tid<512) hf = ld2(Hg + (size_t)pr*16384 + bB*512 + (tid-256)*2);
      if (tid==0)  Zl = ld1(Z_acc + pr*32 + bB);
      if (tid<64)  coldv[tid] = xA[s0+tid];
      if (tid==0)  Zsh = Zl;
      __syncthreads();
      const float Z = Zsh;
      if (tid<256){ xA[tid*2] = cf.x/Z; xA[tid*2+1] = cf.y/Z; }
      else if (tid<512){ xA[512+(tid-256)*2] = hf.x; xA[512+(tid-256)*2+1] = hf.y; }
      __syncthreads();
      if (tid<64){
        const int j = s0+tid;
        float cxj = xA[j];
        __builtin_nontemporal_store(f2bf(cxj), hc_bf + ((size_t)(t-1)*Bq+bB)*1024 + 512 + j);
        float a = wsv[tid]/Z;
        __builtin_nontemporal_store(a, attn_ws + ((size_t)(t-1)*Bq+bB)*Sq + j);
        covb[tid] = (t==1) ? a : covb[tid]+a;
        float part = cxj*Wpgen[j] + hsl[tid]*Wpgen[512+j]
                   + csl[tid]*Wpgen[1024+j] + coldv[tid]*Wxp[j];
        #pragma unroll
        for (int off=32; off>0; off>>=1) part += __shfl_down(part, off);
        if (tid==0) atadd(pgen_raw + (t-1)*Bq + bB, part);
      }
      if (tid<64) st1(ctx_acc + (size_t)(t&1)*16384 + bB*512 + s0+tid, 0.f);
      if (tid==0 && sc==0) st1(Z_acc + (t&1)*32 + bB, 0.f);
      __syncthreads();
    }
    // gate GEMV slice: 256 cols x 4 k-quarters
    {
      float acc = 0.f;
      #pragma unroll 8
      for (int kb=0; kb<32; ++kb){
        bf16x8 w8 = *(const bf16x8*)(wbase + (size_t)kb*2048);
        const u16* ph = (const u16*)&w8;
        float4 x0 = *(const float4*)(xs + kb*8);
        float4 x1 = *(const float4*)(xs + kb*8 + 4);
        acc += x0.x*bf2f(ph[0]) + x0.y*bf2f(ph[1]) + x0.z*bf2f(ph[2]) + x0.w*bf2f(ph[3])
             + x1.x*bf2f(ph[4]) + x1.y*bf2f(ph[5]) + x1.z*bf2f(ph[6]) + x1.w*bf2f(ph[7]);
      }
      zl4[kq][colL] = acc;
    }
    __syncthreads();
    // LSTM own 64 cols
    if (tid<64){
      const int colg = s0 + tid;
      const float* ez = embz + ((size_t)t*Bq + bB)*2048 + colg;
      float zi = (zl4[0][tid*4+0]+zl4[1][tid*4+0])+(zl4[2][tid*4+0]+zl4[3][tid*4+0])
               + __builtin_nontemporal_load(ez);
      float zf = (zl4[0][tid*4+1]+zl4[1][tid*4+1])+(zl4[2][tid*4+1]+zl4[3][tid*4+1])
               + __builtin_nontemporal_load(ez+512);
      float zg = (zl4[0][tid*4+2]+zl4[1][tid*4+2])+(zl4[2][tid*4+2]+zl4[3][tid*4+2])
               + __builtin_nontemporal_load(ez+1024);
      float zo = (zl4[0][tid*4+3]+zl4[1][tid*4+3])+(zl4[2][tid*4+3]+zl4[3][tid*4+3])
               + __builtin_nontemporal_load(ez+1536);
      float co = csl[tid];
      float cn = sigmoidf_(zf)*co + sigmoidf_(zi)*tanhf_(zg);
      float hn = sigmoidf_(zo)*tanhf_(cn);
      csl[tid] = cn;
      hsl[tid] = hn;
      st1(Hg + (size_t)(t&1)*16384 + bB*512 + colg, hn);
      __builtin_nontemporal_store(f2bf(hn), hc_bf + ((size_t)t*Bq+bB)*1024 + colg);
    }
    __syncthreads();
    // df k-partial over own h/c slice
    {
      const int j = tid & 511, half = tid >> 9;
      const float* st = half ? csl : hsl;
      const u16* wa = WAbf + (size_t)(half*512 + s0)*512 + j;
      float acc = 0.f;
      #pragma unroll 8
      for (int k=0;k<64;++k) acc += st[k]*bf2f(wa[(size_t)k*512]);
      dfp[tid] = acc;
    }
    __syncthreads();
    if (tid<512) atadd(df_acc + (size_t)(t&1)*16384 + bB*512 + tid, dfp[tid]+dfp[512+tid]);
    ++mt; mbar(gs, sc, mt);
    //================= PHASE 2 =================
    if (tid<256){
      float2 f = ld2(df_acc + (size_t)(t&1)*16384 + bB*512 + tid*2);
      dfl[tid*2]=f.x; dfl[tid*2+1]=f.y;
    } else if (tid>=960){
      st1(df_acc + (size_t)((t+1)&1)*16384 + bB*512 + s0 + (tid-960), 0.f);
    }
    __syncthreads();
    // e-pass: 16 waves x 4 s-rows
    {
      float dd[8];
      *(float4*)&dd[0] = *(const float4*)&dfl[j0l];
      *(float4*)&dd[4] = *(const float4*)&dfl[j0l+4];
      const u16* efb = EFbf + ((size_t)(bB*512 + s0))*512;
      #pragma unroll
      for (int r=0;r<4;++r){
        int sl = wv*4 + r;
        uint4 pack = *(const uint4*)(efb + (size_t)sl*512 + j0l);
        const u16* ph = (const u16*)&pack;
        float a8 = 0.f;
        if (t>0){
          float cvs = covb[sl];
          #pragma unroll
          for (int q=0;q<8;++q) a8 += vvr[q]*tanhf_(bf2f(ph[q])+dd[q]+cvs*wcr[q]+bcr[q]);
        } else {
          #pragma unroll
          for (int q=0;q<8;++q) a8 += vvr[q]*tanhf_(bf2f(ph[q])+dd[q]);
        }
        #pragma unroll
        for (int off=32; off>0; off>>=1) a8 += __shfl_down(a8, off);
        if (lane==0) el[sl] = a8;
      }
    }
    __syncthreads();
    // no-max weights + Z atomic
    if (tid<64){
      float w_ = mask[bB*512+s0+tid]*__expf(el[tid]);
      wsv[tid] = w_;
      float Zc = w_;
      #pragma unroll
      for (int off=32; off>0; off>>=1) Zc += __shfl_xor(Zc, off);
      if (tid==0) atadd(Z_acc + (t&1)*32 + bB, Zc);
    }
    __syncthreads();
    // ctx partial
    {
      const int j = tid & 511, sh = tid >> 9;
      const u16* efc = EFbf + ((size_t)(bB*512 + s0 + sh*32))*512 + j;
      float acc = 0.f;
      #pragma unroll 4
      for (int s=0;s<32;++s) acc += wsv[sh*32+s]*bf2f(efc[(size_t)s*512]);
      ctp[tid] = acc;
    }
    __syncthreads();
    if (tid<512) atadd(ctx_acc + (size_t)(t&1)*16384 + bB*512 + tid, ctp[tid]+ctp[512+tid]);
    ++mt; mbar(gs, sc, mt);
  }
  //================= epilogue =================
  {
    const int pr = (Tq-1)&1;
    float2 cf; float Zl = 0.f;
    if (tid<256) cf = ld2(ctx_acc + (size_t)pr*16384 + bB*512 + tid*2);
    if (tid==0)  Zl = ld1(Z_acc + pr*32 + bB);
    if (tid<64)  coldv[tid] = xA[s0+tid];
    if (tid==0)  Zsh = Zl;
    __syncthreads();
    const float Z = Zsh;
    if (tid<256){ xA[tid*2] = cf.x/Z; xA[tid*2+1] = cf.y/Z; }
    __syncthreads();
    if (tid<64){
      const int j = s0+tid;
      float cxj = xA[j];
      __builtin_nontemporal_store(f2bf(cxj), hc_bf + ((size_t)(Tq-1)*Bq+bB)*1024 + 512 + j);
      float a = wsv[tid]/Z;
      __builtin_nontemporal_store(a, attn_ws + ((size_t)(Tq-1)*Bq+bB)*Sq + j);
      float part = cxj*Wpgen[j] + hsl[tid]*Wpgen[512+j]
                 + csl[tid]*Wpgen[1024+j] + coldv[tid]*Wxp[j];
      #pragma unroll
      for (int off=32; off>0; off>>=1) part += __shfl_down(part, off);
      if (tid==0) atadd(pgen_raw + (Tq-1)*Bq + bB, part);
    }
  }
}

// ---- W_proj f32 [512][50000] -> WT bf16 [FULL_N][512] (full vocab, zero-pad) ----
__global__ __launch_bounds__(256) void k_wcvt(const float* __restrict__ Wp,
    u16* __restrict__ WT){
  __shared__ float T[32][33];
  const int n0 = blockIdx.x*32, k0 = blockIdx.y*32;
  const int tid = threadIdx.x;
  #pragma unroll
  for (int it=0; it<4; ++it){
    int id = tid + it*256;
    int kk = id>>5, nn = id&31;
    int gn = n0 + nn;
    T[kk][nn] = (gn < VOCABq)
      ? __builtin_nontemporal_load(Wp + (size_t)(k0+kk)*VOCABq + gn) : 0.f;
  }
  __syncthreads();
  #pragma unroll
  for (int it=0; it<4; ++it){
    int id = tid + it*256;
    int nn = id>>5, kk = id&31;
    __builtin_nontemporal_store(f2bf(T[kk][nn]), WT + (size_t)(n0+nn)*512 + k0+kk);
  }
}

// ---- probs_un = exp(Abf @ WT^T + b_proj) -> d_out rows; rowsum partial atomics ----
__global__ __launch_bounds__(256) void k_projs(const u16* __restrict__ Abf,
    const u16* __restrict__ WT, const float* __restrict__ b_proj,
    float* __restrict__ out, float* __restrict__ rowsum){
  __shared__ u16 As[128*40];
  __shared__ u16 Bs[128*40];
  const int tid = threadIdx.x;
  const int m0 = blockIdx.x * 128;
  const int n0 = blockIdx.y * 128;
  const int wid = tid>>6, lane = tid&63;
  const int wm = (wid>>1)*64, wn = (wid&1)*64;
  const int l15 = lane&15, l4 = lane>>4;
  f32x4 acc[4][4];
  #pragma unroll
  for (int mi=0;mi<4;++mi)
    #pragma unroll
    for (int ni=0;ni<4;++ni) acc[mi][ni] = (f32x4){0.f,0.f,0.f,0.f};

  for (int kt=0; kt<16; ++kt){
    const int k0 = kt*32;
    __syncthreads();
    #pragma unroll
    for (int it=0; it<2; ++it){
      int id = tid + it*256;
      int row = id>>2, c4 = id&3;
      uint4 va = *(const uint4*)(Abf + (size_t)(m0+row)*512 + k0 + c4*8);
      *(uint4*)(&As[row*40 + c4*8]) = va;
      uint4 vb = *(const uint4*)(WT + (size_t)(n0+row)*512 + k0 + c4*8);
      *(uint4*)(&Bs[row*40 + c4*8]) = vb;
    }
    __syncthreads();
    bf16x8 a[4], b[4];
    #pragma unroll
    for (int mi=0;mi<4;++mi)
      a[mi] = *(const bf16x8*)(&As[(wm + mi*16 + l15)*40 + l4*8]);
    #pragma unroll
    for (int ni=0;ni<4;++ni)
      b[ni] = *(const bf16x8*)(&Bs[(wn + ni*16 + l15)*40 + l4*8]);
    #pragma unroll
    for (int mi=0;mi<4;++mi)
      #pragma unroll
      for (int ni=0;ni<4;++ni)
        acc[mi][ni] = __builtin_amdgcn_mfma_f32_16x16x32_bf16(a[mi], b[ni], acc[mi][ni], 0,0,0);
  }

  float prow[4][4];
  #pragma unroll
  for (int mi=0;mi<4;++mi)
    #pragma unroll
    for (int r=0;r<4;++r) prow[mi][r]=0.f;

  #pragma unroll
  for (int ni=0;ni<4;++ni){
    const int col = n0 + wn + ni*16 + l15;
    const bool ok = (col < VOCABq);
    const float bp = ok ? b_proj[col] : 0.f;
    #pragma unroll
    for (int mi=0;mi<4;++mi){
      const int rbase = m0 + wm + mi*16 + l4*4;
      #pragma unroll
      for (int r=0;r<4;++r){
        float p = ok ? __expf(acc[mi][ni][r] + bp) : 0.f;
        if (ok) out[(size_t)(rbase+r)*VEXTq + col] = p;
        prow[mi][r] += p;
      }
    }
  }
  #pragma unroll
  for (int mi=0;mi<4;++mi)
    #pragma unroll
    for (int r=0;r<4;++r){
      float v = prow[mi][r];
      v += __shfl_xor(v,1); v += __shfl_xor(v,2);
      v += __shfl_xor(v,4); v += __shfl_xor(v,8);
      if (l15==0) atadd(rowsum + m0 + wm + mi*16 + l4*4 + r, v);
    }
}

// ---- single-pass finalize (f32x4, NT): scale, zero OOV, scatter ----
__global__ __launch_bounds__(256) void k_sm2(float* __restrict__ out,
    const float* __restrict__ rowsum, const float* __restrict__ pgen_raw,
    const float* __restrict__ embxp, const float* __restrict__ attn_ws,
    const int* __restrict__ enc_ids){
  const int row=blockIdx.x, tid=threadIdx.x;
  const int b = row & (Bq-1);
  float* orow = out + (size_t)row*VEXTq;
  const float pg = sigmoidf_(pgen_raw[row] + embxp[row]);
  const float scale = pg / rowsum[row];
  f32x4* o4 = (f32x4*)orow;
  for (int i=tid;i<VOCABq/4;i+=256){
    f32x4 v = __builtin_nontemporal_load(o4 + i);
    v *= scale;
    __builtin_nontemporal_store(v, o4 + i);
  }
  for (int i=VOCABq+tid;i<VEXTq;i+=256) orow[i] = 0.f;
  __syncthreads();
  const float w1 = 1.f-pg;
  const float* arow = attn_ws + (size_t)row*Sq;
  const int* ids = enc_ids + b*Sq;
  for (int si=tid; si<Sq; si+=256)
    atomicAdd(&orow[ids[si]], w1*arow[si]);
}

extern "C" void kernel_launch(void* const* d_in, const int* in_sizes, int n_in,
                              void* d_out, int out_size, void* d_ws, size_t ws_size,
                              hipStream_t stream) {
  (void)in_sizes; (void)n_in; (void)out_size; (void)ws_size;
  const int*   dec_ids    = (const int*)  d_in[0];
  const int*   enc_ids    = (const int*)  d_in[1];
  const float* enc_states = (const float*)d_in[2];
  const float* mask       = (const float*)d_in[3];
  const float* init_h     = (const float*)d_in[4];
  const float* init_c     = (const float*)d_in[5];
  const float* embeddings = (const float*)d_in[6];
  const float* W_enc      = (const float*)d_in[7];
  const float* b_enc      = (const float*)d_in[8];
  const float* W_attn     = (const float*)d_in[9];
  const float* vvec       = (const float*)d_in[10];
  const float* w_cov      = (const float*)d_in[11];
  const float* b_cov      = (const float*)d_in[12];
  const float* W_x        = (const float*)d_in[13];
  const float* W_out      = (const float*)d_in[14];
  const float* Wk         = (const float*)d_in[15];
  const float* Wr         = (const float*)d_in[16];
  const float* b_lstm     = (const float*)d_in[17];
  const float* W_pgen     = (const float*)d_in[18];
  const float* W_proj     = (const float*)d_in[19];
  const float* b_proj     = (const float*)d_in[20];
  float* out = (float*)d_out;
  float* ws  = (float*)d_ws;

  u16*   EFbf    = (u16*)ws;
  float* attn_ws = ws + 4194304;
  u16*   hc_bf   = (u16*)(attn_ws + 524288);
  u16*   outm_bf = (u16*)(attn_ws + 524288 + 524288);
  u16*   embx_bf = (u16*)(attn_ws + 524288 + 524288 + 262144);
  float* embxp   = attn_ws + 524288 + 524288 + 262144 + 262144;
  float* embz    = embxp + 1024;
  float* WXKT_   = embz + 2097152;
  float* WrT_    = WXKT_ + 1048576;
  u16*   WkT     = (u16*)(WrT_ + 1048576);
  u16*   Xb      = (u16*)(((float*)WkT) + 524288);
  u16*   WoT     = (u16*)(((float*)Xb) + 131072);
  float* Wxp     = ((float*)WoT) + 262144;
  float* Hg      = Wxp + 512;
  unsigned* msl  = (unsigned*)(Hg + 32768);
  float* pgen_raw= (float*)(msl + 512);
  float* ctx_acc = pgen_raw + 1024;
  float* df_acc  = ctx_acc + 32768;
  float* Z_acc   = df_acc + 32768;
  float* rowsum  = Z_acc + 64;
  u16*   WGC     = (u16*)(rowsum + 1024);
  u16*   WAbf    = (u16*)(((float*)WGC) + 1048576);
  u16*   WET     = (u16*)(((float*)WAbf) + 262144);
  u16*   WT      = (u16*)(((float*)WET) + 131072);   // FULL_N*512 u16

  hipMemsetAsync(msl, 0, (512 + 1024 + 32768 + 32768 + 64 + 1024)*sizeof(unsigned), stream);

  // ---- precompute ----
  k_prep<<<3840, 256, 0, stream>>>(W_enc, WET, Wk, WkT, W_out, WoT, W_attn, WAbf);
  {
    dim3 g(128,4);
    k_encm<<<g, 256, 0, stream>>>(enc_states, WET, b_enc, EFbf);
  }
  k_embx<<<64, 512, 0, stream>>>(dec_ids, embeddings, W_x, W_pgen, embx_bf, embxp);
  k_wx2c<<<512, 512, 0, stream>>>(W_x, W_pgen, Xb, Wxp);
  {
    dim3 g(8,16);
    k_gemm512<<<g, 256, 0, stream>>>(embx_bf, WkT, b_lstm, embz, 2048, 1);
  }
  {
    dim3 g(16,4);
    k_gemm512<<<g, 256, 0, stream>>>(WkT, Xb, (const float*)0, WXKT_, 512, 0);
  }
  {
    dim3 g(64,16);
    k_trans<<<g, 512, 0, stream>>>(Wr, WrT_, 512, 2048);
  }
  k_wgc<<<2048, 512, 0, stream>>>(WXKT_, WrT_, WGC);

  // ---- recurrence: 256 blocks x 1024 threads (verified structure) ----
  {
    void* args[] = { (void*)&EFbf, (void*)&mask, (void*)&init_h, (void*)&init_c,
                     (void*)&WGC, (void*)&embz, (void*)&WAbf, (void*)&vvec,
                     (void*)&w_cov, (void*)&b_cov, (void*)&W_pgen, (void*)&Wxp,
                     (void*)&Hg, (void*)&ctx_acc, (void*)&df_acc, (void*)&Z_acc,
                     (void*)&hc_bf, (void*)&attn_ws, (void*)&pgen_raw,
                     (void*)&msl };
    hipLaunchCooperativeKernel((void*)k_rec9, dim3(256), dim3(1024), args, 0, stream);
  }

  // ---- output projection (MFMA mid + single full-vocab conv/proj) + finalize ----
  {
    dim3 g(8,4);
    k_gemmb<<<g, 256, 0, stream>>>(hc_bf, WoT, outm_bf, 1024, 512);
  }
  {
    dim3 gc(FULL_N/32, 16);
    k_wcvt<<<gc, 256, 0, stream>>>(W_proj, WT);
  }
  {
    dim3 gp(8, FULL_N/128);
    k_projs<<<gp, 256, 0, stream>>>(outm_bf, WT, b_proj, out, rowsum);
  }
  k_sm2<<<Tq*Bq, 256, 0, stream>>>(out, rowsum, pgen_raw, embxp, attn_ws, enc_ids);
}